// Round 8
// baseline (439.290 us; speedup 1.0000x reference)
//
#include <hip/hip_runtime.h>
#include <hip/hip_bf16.h>

typedef float f32x4 __attribute__((ext_vector_type(4)));
typedef __bf16 bf16x8 __attribute__((ext_vector_type(8)));
typedef unsigned int u32;
typedef u32 u32x4 __attribute__((ext_vector_type(4)));

// ws layout (bf16 element offsets)
#define PK1  0        // g1w plain   [kt<64][n<4]     256 KB
#define PK2  131072   // g2w plain   [t<2][n<2]       4 KB
#define PK3  133120   // bw   hi/lo  [kt<16][n<8][hl] 256 KB (main reads hi only)
#define PK4  264192   // n1w  hi/lo  [t<4][n<4][hl]   32 KB  (hi only)
#define PK5  280576   // mw   hi/lo  [t<2][n<2][hl]   8 KB   (hi only)
#define PK6V 284672   // v1w  hi/lo  [hl]             2 KB   (hi only)
#define PK6A 285696   // a1w  hi/lo  [hl]             2 KB   (hi only)

#define ASTR 260      // per-row LDS stride in f32 (65 x 16B chunks, odd -> 8-way spread)

__device__ __forceinline__ f32x4 mfma16(bf16x8 a, bf16x8 b, f32x4 c) {
    return __builtin_amdgcn_mfma_f32_16x16x32_bf16(a, b, c, 0, 0, 0);
}
__device__ __forceinline__ float redsum16(float v) {
    v += __shfl_xor(v, 1); v += __shfl_xor(v, 2);
    v += __shfl_xor(v, 4); v += __shfl_xor(v, 8);
    return v;
}
__device__ __forceinline__ unsigned short bfb(__bf16 b) {
    return __builtin_bit_cast(unsigned short, b);
}
__device__ __forceinline__ bf16x8 cvt8(f32x4 a, f32x4 b) {
    bf16x8 r;
    r[0]=(__bf16)a[0]; r[1]=(__bf16)a[1]; r[2]=(__bf16)a[2]; r[3]=(__bf16)a[3];
    r[4]=(__bf16)b[0]; r[5]=(__bf16)b[1]; r[6]=(__bf16)b[2]; r[7]=(__bf16)b[3];
    return r;
}
__device__ __forceinline__ void split8(f32x4 a, f32x4 b, bf16x8& h, bf16x8& l) {
    #pragma unroll
    for (int e=0;e<4;++e){ __bf16 hb=(__bf16)a[e]; h[e]=hb; l[e]=(__bf16)(a[e]-(float)hb); }
    #pragma unroll
    for (int e=0;e<4;++e){ __bf16 hb=(__bf16)b[e]; h[4+e]=hb; l[4+e]=(__bf16)(b[e]-(float)hb); }
}
__device__ __forceinline__ void unpack8(u32x4 w0, u32x4 w1, bf16x8& h, bf16x8& l) {
    u32 h0=(w0[0]&0xFFFFu)|(w0[1]<<16), h1=(w0[2]&0xFFFFu)|(w0[3]<<16);
    u32 h2=(w1[0]&0xFFFFu)|(w1[1]<<16), h3=(w1[2]&0xFFFFu)|(w1[3]<<16);
    u32 l0=(w0[0]>>16)|(w0[1]&0xFFFF0000u), l1=(w0[2]>>16)|(w0[3]&0xFFFF0000u);
    u32 l2=(w1[0]>>16)|(w1[1]&0xFFFF0000u), l3=(w1[2]>>16)|(w1[3]&0xFFFF0000u);
    u32x4 hv={h0,h1,h2,h3}, lv={l0,l1,l2,l3};
    h=__builtin_bit_cast(bf16x8,hv); l=__builtin_bit_cast(bf16x8,lv);
}

// ---------------- weight pre-pack (one-time per launch, ~5 us) --------------
__device__ __forceinline__ void pack_plain(const float* __restrict__ W, __bf16* __restrict__ dst,
                                           int i, int K, int Nn) {
    int e=i&7, lane=(i>>3)&63, p=i>>9;
    int n=p%Nn, t=p/Nn;
    float v = W[(size_t)(n*16+(lane&15))*K + t*32 + (lane>>4)*8 + e];
    dst[i] = (__bf16)v;
}
__device__ __forceinline__ void pack_hilo(const float* __restrict__ W, __bf16* __restrict__ dst,
                                          int i, int K, int Nn) {
    int e=i&7, lane=(i>>3)&63, p=i>>9;
    int n=p%Nn, t=p/Nn;
    float v = W[(size_t)(n*16+(lane&15))*K + t*32 + (lane>>4)*8 + e];
    __bf16 h = (__bf16)v;
    dst[p*1024 + (i&511)]       = h;
    dst[p*1024 + 512 + (i&511)] = (__bf16)(v - (float)h);
}
__global__ void pack_weights(const float* g1w, const float* g2w, const float* bw,
                             const float* n1w, const float* mw, const float* v1w,
                             const float* a1w, __bf16* wsb) {
    int gi = blockIdx.x*256 + threadIdx.x;
    if      (gi < 131072) pack_plain(g1w, wsb+PK1, gi,          2048, 4);
    else if (gi < 133120) pack_plain(g2w, wsb+PK2, gi-131072,   64,   2);
    else if (gi < 198656) pack_hilo (bw,  wsb+PK3, gi-133120,   512,  8);
    else if (gi < 206848) pack_hilo (n1w, wsb+PK4, gi-198656,   128,  4);
    else if (gi < 208896) pack_hilo (mw,  wsb+PK5, gi-206848,   64,   2);
    else if (gi < 209408) pack_hilo (v1w, wsb+PK6V, gi-208896,  32,   1);
    else if (gi < 209920) pack_hilo (a1w, wsb+PK6A, gi-209408,  32,   1);
}

// ---------------- fused main kernel: barrier-free, 16 rows per wave ---------
// One full LDS row per load instruction: 64 lanes x 16B = 1 KB CONTIGUOUS burst
// per row visit (DRAM-page friendly). Grid 512 = exactly 2 blocks/CU resident;
// each block loops 2 row-groups. Compiler-scheduled (no fences, r4 lesson).
__global__ __launch_bounds__(256, 2)
void gated_dqn_main(const float* __restrict__ x,   const float* __restrict__ hist,
                    const float* __restrict__ g1b, const float* __restrict__ g2b,
                    const float* __restrict__ bb,  const float* __restrict__ ln1g,
                    const float* __restrict__ ln1b,const float* __restrict__ n1b,
                    const float* __restrict__ ln2g,const float* __restrict__ ln2b,
                    const float* __restrict__ mb,  const float* __restrict__ v1b,
                    const float* __restrict__ v2w, const float* __restrict__ v2b,
                    const float* __restrict__ a1b, const float* __restrict__ a2w,
                    const float* __restrict__ a2b, const __bf16* __restrict__ wsb,
                    float* __restrict__ qout, float* __restrict__ gateout)
{
    __shared__ __align__(16) float scr[4][16*ASTR];   // 16.25 KB per wave, 65 KB/block
    const int tid = threadIdx.x, lane = tid & 63, wv = tid >> 6;
    const int qq = lane >> 4, c = lane & 15;
    float*  myA = scr[wv];
    u32*    my  = (u32*)myA;
    __bf16* myb = (__bf16*)myA;
    const int swc = ((c >> 1) & 3) << 3;           // activation-scratch swizzle

    for (int it = 0; it < 2; ++it) {
    const int r0 = ((it*512 + blockIdx.x)*4 + wv)*16;

    // ===== Phase 1: h = relu(hist @ g1w^T + g1b)   [16x64, K=2048]
    // 8 groups of 256 f32/row; 1 KB contiguous per row per load instr.
    f32x4 acc[4] = {};
    {
        const float* aG = hist + (size_t)r0*2048 + lane*4;
        f32x4 rg[16];
        #pragma unroll
        for (int i = 0; i < 16; ++i) rg[i] = *(const f32x4*)(aG + (size_t)i*2048);
        const __bf16* bB = wsb + PK1 + lane*8;
        bf16x8 cb0 = *(const bf16x8*)(bB),      cb1 = *(const bf16x8*)(bB+512);
        bf16x8 cb2 = *(const bf16x8*)(bB+1024), cb3 = *(const bf16x8*)(bB+1536);
        for (int g = 0; g < 8; ++g) {
            #pragma unroll
            for (int i = 0; i < 16; ++i)
                *(f32x4*)&myA[i*ASTR + lane*4] = rg[i];
            if (g + 1 < 8) {
                #pragma unroll
                for (int i = 0; i < 16; ++i)
                    rg[i] = *(const f32x4*)(aG + (size_t)i*2048 + (g+1)*256);
            }
            #pragma unroll
            for (int t = 0; t < 8; ++t) {
                int ktn = g*8 + t + 1; if (ktn > 63) ktn = 63;
                const __bf16* btn = bB + (size_t)ktn*2048;
                bf16x8 nb0 = *(const bf16x8*)(btn),      nb1 = *(const bf16x8*)(btn+512);
                bf16x8 nb2 = *(const bf16x8*)(btn+1024), nb3 = *(const bf16x8*)(btn+1536);
                f32x4 lo = *(const f32x4*)&myA[c*ASTR + t*32 + qq*8];
                f32x4 hi = *(const f32x4*)&myA[c*ASTR + t*32 + qq*8 + 4];
                bf16x8 af = cvt8(lo, hi);
                acc[0] = mfma16(af, cb0, acc[0]); acc[1] = mfma16(af, cb1, acc[1]);
                acc[2] = mfma16(af, cb2, acc[2]); acc[3] = mfma16(af, cb3, acc[3]);
                cb0 = nb0; cb1 = nb1; cb2 = nb2; cb3 = nb3;
            }
        }
        #pragma unroll
        for (int n = 0; n < 4; ++n) {
            float bv = g1b[n*16 + c];
            #pragma unroll
            for (int j = 0; j < 4; ++j) {
                int r = qq*4 + j, col = n*16 + c;
                myb[r*64 + (col ^ (((r>>1)&3)<<3))] = (__bf16)fmaxf(acc[n][j] + bv, 0.0f);
            }
        }
    }

    // ===== Phase 2: gate = sigmoid(h @ g2w^T + g2b), mod
    float mj[4];
    {
        const __bf16* bB = wsb + PK2 + lane*8;
        bf16x8 a0 = *(const bf16x8*)&myb[c*64 + ((qq*8) ^ swc)];
        bf16x8 a1 = *(const bf16x8*)&myb[c*64 + ((32 + qq*8) ^ swc)];
        bf16x8 b00 = *(const bf16x8*)(bB),      b01 = *(const bf16x8*)(bB+512);
        bf16x8 b10 = *(const bf16x8*)(bB+1024), b11 = *(const bf16x8*)(bB+1536);
        f32x4 ag0 = {}, ag1 = {};
        ag0 = mfma16(a0, b00, ag0); ag1 = mfma16(a0, b01, ag1);
        ag0 = mfma16(a1, b10, ag0); ag1 = mfma16(a1, b11, ag1);
        float s[4] = {0,0,0,0};
        #pragma unroll
        for (int n = 0; n < 2; ++n) {
            float bv = g2b[n*16 + c];
            f32x4 ag = n ? ag1 : ag0;
            #pragma unroll
            for (int j = 0; j < 4; ++j) {
                float gv = 1.0f / (1.0f + __expf(-(ag[j] + bv)));
                gateout[(size_t)(r0 + qq*4 + j)*32 + n*16 + c] = gv;
                s[j] += gv;
            }
        }
        #pragma unroll
        for (int j = 0; j < 4; ++j)
            mj[j] = 0.7f + 0.3f * redsum16(s[j]) * (1.0f/32.0f);
    }

    // ===== Phase 3: xg = LN1(relu((x @ bw^T)*mod + bb))   [16x128, K=512]
    // 2 groups of 256 f32/row (1 KB bursts). A hi/lo, B hi only.
    f32x4 a3[8] = {};
    {
        const float* aG = x + (size_t)r0*512 + lane*4;
        f32x4 rg[16];
        #pragma unroll
        for (int i = 0; i < 16; ++i) rg[i] = *(const f32x4*)(aG + (size_t)i*512);
        #pragma unroll
        for (int g = 0; g < 2; ++g) {
            #pragma unroll
            for (int i = 0; i < 16; ++i)
                *(f32x4*)&myA[i*ASTR + lane*4] = rg[i];
            if (g + 1 < 2) {
                #pragma unroll
                for (int i = 0; i < 16; ++i)
                    rg[i] = *(const f32x4*)(aG + (size_t)i*512 + 256);
            }
            #pragma unroll
            for (int t = 0; t < 8; ++t) {
                f32x4 lo = *(const f32x4*)&myA[c*ASTR + t*32 + qq*8];
                f32x4 hi = *(const f32x4*)&myA[c*ASTR + t*32 + qq*8 + 4];
                bf16x8 ah, al; split8(lo, hi, ah, al);
                int kt = g*8 + t;
                #pragma unroll
                for (int half = 0; half < 2; ++half) {
                    const __bf16* bt = wsb + PK3 + (size_t)(kt*16 + half*8)*512 + lane*8;
                    #pragma unroll
                    for (int n = 0; n < 4; ++n) {
                        bf16x8 bh = *(const bf16x8*)(bt + n*1024);
                        f32x4 a = a3[half*4 + n];
                        a = mfma16(ah, bh, a); a = mfma16(al, bh, a);
                        a3[half*4 + n] = a;
                    }
                }
            }
        }
        float s[4] = {0,0,0,0}, ss[4] = {0,0,0,0};
        #pragma unroll
        for (int n = 0; n < 8; ++n) {
            float bv = bb[n*16 + c];
            #pragma unroll
            for (int j = 0; j < 4; ++j) {
                float v = fmaxf(a3[n][j]*mj[j] + bv, 0.0f);
                a3[n][j] = v; s[j] += v; ss[j] += v*v;
            }
        }
        float mean[4], rstd[4];
        #pragma unroll
        for (int j = 0; j < 4; ++j) {
            float t = redsum16(s[j]), t2 = redsum16(ss[j]);
            float m = t * (1.0f/128.0f);
            mean[j] = m; rstd[j] = rsqrtf(t2*(1.0f/128.0f) - m*m + 1e-5f);
        }
        #pragma unroll
        for (int n = 0; n < 8; ++n) {
            float g = ln1g[n*16 + c], b2 = ln1b[n*16 + c];
            #pragma unroll
            for (int j = 0; j < 4; ++j) {
                int r = qq*4 + j, col = n*16 + c;
                float y = (a3[n][j] - mean[j]) * rstd[j] * g + b2;
                __bf16 hb = (__bf16)y; __bf16 lb = (__bf16)(y - (float)hb);
                my[r*128 + (col ^ (((r>>1)&3)<<3))] = (u32)bfb(hb) | ((u32)bfb(lb) << 16);
            }
        }
    }

    // ===== Phase 4: f = LN2(relu(xg @ n1w^T + n1b))   [16x64, K=128]
    f32x4 a4[4] = {};
    {
        const __bf16* bB = wsb + PK4 + lane*8;
        #pragma unroll
        for (int t = 0; t < 4; ++t) {
            int base = c*128 + ((t*32 + qq*8) ^ swc);
            u32x4 w0 = *(const u32x4*)&my[base], w1 = *(const u32x4*)&my[base + 4];
            bf16x8 ah, al; unpack8(w0, w1, ah, al);
            const __bf16* bt = bB + t*4096;
            #pragma unroll
            for (int n = 0; n < 4; ++n) {
                bf16x8 bh = *(const bf16x8*)(bt + n*1024);
                f32x4 a = a4[n];
                a = mfma16(ah, bh, a); a = mfma16(al, bh, a);
                a4[n] = a;
            }
        }
        float s[4] = {0,0,0,0}, ss[4] = {0,0,0,0};
        #pragma unroll
        for (int n = 0; n < 4; ++n) {
            float bv = n1b[n*16 + c];
            #pragma unroll
            for (int j = 0; j < 4; ++j) {
                float v = fmaxf(a4[n][j] + bv, 0.0f);
                a4[n][j] = v; s[j] += v; ss[j] += v*v;
            }
        }
        float mean[4], rstd[4];
        #pragma unroll
        for (int j = 0; j < 4; ++j) {
            float t = redsum16(s[j]), t2 = redsum16(ss[j]);
            float m = t * (1.0f/64.0f);
            mean[j] = m; rstd[j] = rsqrtf(t2*(1.0f/64.0f) - m*m + 1e-5f);
        }
        #pragma unroll
        for (int n = 0; n < 4; ++n) {
            float g = ln2g[n*16 + c], b2 = ln2b[n*16 + c];
            #pragma unroll
            for (int j = 0; j < 4; ++j) {
                int r = qq*4 + j, col = n*16 + c;
                float y = (a4[n][j] - mean[j]) * rstd[j] * g + b2;
                __bf16 hb = (__bf16)y; __bf16 lb = (__bf16)(y - (float)hb);
                my[r*64 + (col ^ (((r>>1)&3)<<3))] = (u32)bfb(hb) | ((u32)bfb(lb) << 16);
            }
        }
    }

    // ===== Phase 5: features = relu(f @ mw^T + mb)   [16x32, K=64]
    {
        const __bf16* bB = wsb + PK5 + lane*8;
        f32x4 a5[2] = {};
        #pragma unroll
        for (int t = 0; t < 2; ++t) {
            int base = c*64 + ((t*32 + qq*8) ^ swc);
            u32x4 w0 = *(const u32x4*)&my[base], w1 = *(const u32x4*)&my[base + 4];
            bf16x8 ah, al; unpack8(w0, w1, ah, al);
            const __bf16* bt = bB + t*2048;
            #pragma unroll
            for (int n = 0; n < 2; ++n) {
                bf16x8 bh = *(const bf16x8*)(bt + n*1024);
                f32x4 a = a5[n];
                a = mfma16(ah, bh, a); a = mfma16(al, bh, a);
                a5[n] = a;
            }
        }
        #pragma unroll
        for (int n = 0; n < 2; ++n) {
            float bv = mb[n*16 + c];
            #pragma unroll
            for (int j = 0; j < 4; ++j) {
                int r = qq*4 + j, col = n*16 + c;
                float v = fmaxf(a5[n][j] + bv, 0.0f);
                __bf16 hb = (__bf16)v; __bf16 lb = (__bf16)(v - (float)hb);
                my[r*32 + (col ^ (((r>>1)&3)<<3))] = (u32)bfb(hb) | ((u32)bfb(lb) << 16);
            }
        }
    }

    // ===== Phase 6: dueling heads -> q   [K=32]
    {
        int base = c*32 + ((qq*8) ^ swc);
        u32x4 w0 = *(const u32x4*)&my[base], w1 = *(const u32x4*)&my[base + 4];
        bf16x8 ah, al; unpack8(w0, w1, ah, al);
        const __bf16* bv_ = wsb + PK6V + lane*8;
        const __bf16* ba_ = wsb + PK6A + lane*8;
        bf16x8 vh  = *(const bf16x8*)(bv_);
        bf16x8 ahw = *(const bf16x8*)(ba_);
        f32x4 av = {}, aa = {};
        av = mfma16(ah, vh, av);  av = mfma16(al, vh, av);
        aa = mfma16(ah, ahw, aa); aa = mfma16(al, ahw, aa);
        float v1bc = v1b[c], a1bc = a1b[c], w2 = v2w[c];
        float vb2 = v2b[0];
        float aw0 = a2w[c], aw1 = a2w[16+c], aw2 = a2w[32+c], aw3 = a2w[48+c];
        float ab0 = a2b[0], ab1 = a2b[1], ab2 = a2b[2], ab3 = a2b[3];
        #pragma unroll
        for (int j = 0; j < 4; ++j) {
            float hv = fmaxf(av[j] + v1bc, 0.0f);
            float ha = fmaxf(aa[j] + a1bc, 0.0f);
            float val = redsum16(hv * w2) + vb2;
            float d0 = redsum16(ha * aw0) + ab0;
            float d1 = redsum16(ha * aw1) + ab1;
            float d2 = redsum16(ha * aw2) + ab2;
            float d3 = redsum16(ha * aw3) + ab3;
            float ma = 0.25f * (d0 + d1 + d2 + d3);
            if (c == 0) {
                f32x4 qv = {val + d0 - ma, val + d1 - ma, val + d2 - ma, val + d3 - ma};
                *(f32x4*)(qout + (size_t)(r0 + qq*4 + j)*4) = qv;
            }
        }
    }
    } // it loop
}

extern "C" void kernel_launch(void* const* d_in, const int* in_sizes, int n_in,
                              void* d_out, int out_size, void* d_ws, size_t ws_size,
                              hipStream_t stream) {
    (void)in_sizes; (void)n_in; (void)ws_size; (void)out_size;
    const float* x    = (const float*)d_in[0];
    const float* hist = (const float*)d_in[1];
    const float* g1w  = (const float*)d_in[2];
    const float* g1b  = (const float*)d_in[3];
    const float* g2w  = (const float*)d_in[4];
    const float* g2b  = (const float*)d_in[5];
    const float* bw   = (const float*)d_in[6];
    const float* bb   = (const float*)d_in[7];
    const float* ln1g = (const float*)d_in[8];
    const float* ln1b = (const float*)d_in[9];
    const float* n1w  = (const float*)d_in[10];
    const float* n1b  = (const float*)d_in[11];
    const float* ln2g = (const float*)d_in[12];
    const float* ln2b = (const float*)d_in[13];
    const float* mw   = (const float*)d_in[14];
    const float* mb   = (const float*)d_in[15];
    const float* v1w  = (const float*)d_in[16];
    const float* v1b  = (const float*)d_in[17];
    const float* v2w  = (const float*)d_in[18];
    const float* v2b  = (const float*)d_in[19];
    const float* a1w  = (const float*)d_in[20];
    const float* a1b  = (const float*)d_in[21];
    const float* a2w  = (const float*)d_in[22];
    const float* a2b  = (const float*)d_in[23];
    __bf16* wsb = (__bf16*)d_ws;
    float* qout = (float*)d_out;
    float* gateout = qout + (size_t)65536 * 4;

    pack_weights<<<dim3(820), dim3(256), 0, stream>>>(g1w, g2w, bw, n1w, mw, v1w, a1w, wsb);
    gated_dqn_main<<<dim3(512), dim3(256), 0, stream>>>(
        x, hist, g1b, g2b, bb, ln1g, ln1b, n1b, ln2g, ln2b, mb,
        v1b, v2w, v2b, a1b, a2w, a2b, wsb, qout, gateout);
}

// Round 9
// 179.001 us; speedup vs baseline: 2.4541x; 2.4541x over previous
//
#include <hip/hip_runtime.h>
#include <hip/hip_bf16.h>

typedef float f32x4 __attribute__((ext_vector_type(4)));
typedef __bf16 bf16x8 __attribute__((ext_vector_type(8)));
typedef unsigned int u32;
typedef u32 u32x4 __attribute__((ext_vector_type(4)));

// ws layout (bf16 element offsets)
#define PK1  0        // g1w plain   [kt<64][n<4]     256 KB
#define PK2  131072   // g2w plain   [t<2][n<2]       4 KB
#define PK3  133120   // bw   hi/lo  [kt<16][n<8][hl] 256 KB (main reads hi only)
#define PK4  264192   // n1w  hi/lo  [t<4][n<4][hl]   32 KB  (hi only)
#define PK5  280576   // mw   hi/lo  [t<2][n<2][hl]   8 KB   (hi only)
#define PK6V 284672   // v1w  hi/lo  [hl]             2 KB   (hi only)
#define PK6A 285696   // a1w  hi/lo  [hl]             2 KB   (hi only)

__device__ __forceinline__ f32x4 mfma16(bf16x8 a, bf16x8 b, f32x4 c) {
    return __builtin_amdgcn_mfma_f32_16x16x32_bf16(a, b, c, 0, 0, 0);
}
__device__ __forceinline__ float redsum16(float v) {
    v += __shfl_xor(v, 1); v += __shfl_xor(v, 2);
    v += __shfl_xor(v, 4); v += __shfl_xor(v, 8);
    return v;
}
__device__ __forceinline__ unsigned short bfb(__bf16 b) {
    return __builtin_bit_cast(unsigned short, b);
}
__device__ __forceinline__ bf16x8 cvt8(f32x4 a, f32x4 b) {
    bf16x8 r;
    r[0]=(__bf16)a[0]; r[1]=(__bf16)a[1]; r[2]=(__bf16)a[2]; r[3]=(__bf16)a[3];
    r[4]=(__bf16)b[0]; r[5]=(__bf16)b[1]; r[6]=(__bf16)b[2]; r[7]=(__bf16)b[3];
    return r;
}
__device__ __forceinline__ void split8(f32x4 a, f32x4 b, bf16x8& h, bf16x8& l) {
    #pragma unroll
    for (int e=0;e<4;++e){ __bf16 hb=(__bf16)a[e]; h[e]=hb; l[e]=(__bf16)(a[e]-(float)hb); }
    #pragma unroll
    for (int e=0;e<4;++e){ __bf16 hb=(__bf16)b[e]; h[4+e]=hb; l[4+e]=(__bf16)(b[e]-(float)hb); }
}
__device__ __forceinline__ void unpack8(u32x4 w0, u32x4 w1, bf16x8& h, bf16x8& l) {
    u32 h0=(w0[0]&0xFFFFu)|(w0[1]<<16), h1=(w0[2]&0xFFFFu)|(w0[3]<<16);
    u32 h2=(w1[0]&0xFFFFu)|(w1[1]<<16), h3=(w1[2]&0xFFFFu)|(w1[3]<<16);
    u32 l0=(w0[0]>>16)|(w0[1]&0xFFFF0000u), l1=(w0[2]>>16)|(w0[3]&0xFFFF0000u);
    u32 l2=(w1[0]>>16)|(w1[1]&0xFFFF0000u), l3=(w1[2]>>16)|(w1[3]&0xFFFF0000u);
    u32x4 hv={h0,h1,h2,h3}, lv={l0,l1,l2,l3};
    h=__builtin_bit_cast(bf16x8,hv); l=__builtin_bit_cast(bf16x8,lv);
}

// ---------------- weight pre-pack (one-time per launch, ~5 us) --------------
__device__ __forceinline__ void pack_plain(const float* __restrict__ W, __bf16* __restrict__ dst,
                                           int i, int K, int Nn) {
    int e=i&7, lane=(i>>3)&63, p=i>>9;
    int n=p%Nn, t=p/Nn;
    float v = W[(size_t)(n*16+(lane&15))*K + t*32 + (lane>>4)*8 + e];
    dst[i] = (__bf16)v;
}
__device__ __forceinline__ void pack_hilo(const float* __restrict__ W, __bf16* __restrict__ dst,
                                          int i, int K, int Nn) {
    int e=i&7, lane=(i>>3)&63, p=i>>9;
    int n=p%Nn, t=p/Nn;
    float v = W[(size_t)(n*16+(lane&15))*K + t*32 + (lane>>4)*8 + e];
    __bf16 h = (__bf16)v;
    dst[p*1024 + (i&511)]       = h;
    dst[p*1024 + 512 + (i&511)] = (__bf16)(v - (float)h);
}
__global__ void pack_weights(const float* g1w, const float* g2w, const float* bw,
                             const float* n1w, const float* mw, const float* v1w,
                             const float* a1w, __bf16* wsb) {
    int gi = blockIdx.x*256 + threadIdx.x;
    if      (gi < 131072) pack_plain(g1w, wsb+PK1, gi,          2048, 4);
    else if (gi < 133120) pack_plain(g2w, wsb+PK2, gi-131072,   64,   2);
    else if (gi < 198656) pack_hilo (bw,  wsb+PK3, gi-133120,   512,  8);
    else if (gi < 206848) pack_hilo (n1w, wsb+PK4, gi-198656,   128,  4);
    else if (gi < 208896) pack_hilo (mw,  wsb+PK5, gi-206848,   64,   2);
    else if (gi < 209408) pack_hilo (v1w, wsb+PK6V, gi-208896,  32,   1);
    else if (gi < 209920) pack_hilo (a1w, wsb+PK6A, gi-209408,  32,   1);
}

// ---------------- fused main kernel: barrier-free, 16 rows per wave ---------
// Phase 1 FIFO-ordered pipeline: per group, issue order is
//   {ds_write A(g)} -> {B(g+1) loads} -> {A(g+1) loads} -> {MFMA w/ B(g) regs}
// so the only VMEM wait per group (at the ds_write) targets loads issued one
// full group-period ago, and waiting on nothing ever force-drains the A stream.
__global__ __launch_bounds__(256, 2)
void gated_dqn_main(const float* __restrict__ x,   const float* __restrict__ hist,
                    const float* __restrict__ g1b, const float* __restrict__ g2b,
                    const float* __restrict__ bb,  const float* __restrict__ ln1g,
                    const float* __restrict__ ln1b,const float* __restrict__ n1b,
                    const float* __restrict__ ln2g,const float* __restrict__ ln2b,
                    const float* __restrict__ mb,  const float* __restrict__ v1b,
                    const float* __restrict__ v2w, const float* __restrict__ v2b,
                    const float* __restrict__ a1b, const float* __restrict__ a2w,
                    const float* __restrict__ a2b, const __bf16* __restrict__ wsb,
                    float* __restrict__ qout, float* __restrict__ gateout)
{
    __shared__ __align__(16) float scr[4][2112];   // 8.25 KB per wave (aliased views)
    const int tid = threadIdx.x, lane = tid & 63, wv = tid >> 6;
    const int qq = lane >> 4, c = lane & 15;
    const int r0 = (blockIdx.x*4 + wv)*16;
    float*  myA = scr[wv];
    u32*    my  = (u32*)myA;
    __bf16* myb = (__bf16*)myA;
    const int swc = ((c >> 1) & 3) << 3;           // activation-scratch swizzle
    const int srl = lane >> 3, scl = lane & 7;     // coalesced-stage role: row, 16B-chunk

    // ===== Phase 1: h = relu(hist @ g1w^T + g1b)   [16x64, K=2048]
    // 16 groups of 128 f32/row; stage stride 130 words (2 mod 32 -> <=4-way banks).
    f32x4 acc[4] = {};
    {
        const float* aRow0 = hist + (size_t)(r0 + srl)*2048 + scl*4;
        const float* aRow1 = hist + (size_t)(r0 + 8 + srl)*2048 + scl*4;
        const __bf16* bB = wsb + PK1 + lane*8;
        f32x4 rg[8];
        bf16x8 Bcur[16], Bnext[16];
        // prologue: B(0) first, then A(0) (B older in FIFO than A)
        #pragma unroll
        for (int i = 0; i < 16; ++i)
            Bcur[i] = *(const bf16x8*)(bB + (size_t)i*512);
        #pragma unroll
        for (int q = 0; q < 4; ++q) {
            rg[q]   = *(const f32x4*)(aRow0 + q*32);
            rg[4+q] = *(const f32x4*)(aRow1 + q*32);
        }
        auto body = [&](int g, bf16x8* Bc, bf16x8* Bn) {
            // stage A(g) (compiler waits here on A(g) loads; B(g) is older -> done)
            #pragma unroll
            for (int q = 0; q < 4; ++q) {
                *(f32x4*)&myA[srl*130     + q*32 + scl*4] = rg[q];
                *(f32x4*)&myA[(8+srl)*130 + q*32 + scl*4] = rg[4+q];
            }
            if (g + 1 < 16) {
                #pragma unroll
                for (int i = 0; i < 16; ++i)     // B(g+1) BEFORE A(g+1)
                    Bn[i] = *(const bf16x8*)(bB + (size_t)(g+1)*8192 + i*512);
                #pragma unroll
                for (int q = 0; q < 4; ++q) {
                    rg[q]   = *(const f32x4*)(aRow0 + (g+1)*128 + q*32);
                    rg[4+q] = *(const f32x4*)(aRow1 + (g+1)*128 + q*32);
                }
            }
            // compute with B(g) already in registers: no VMEM waits here
            #pragma unroll
            for (int t = 0; t < 4; ++t) {
                f32x4 lo = *(const f32x4*)&myA[c*130 + t*32 + qq*8];
                f32x4 hi = *(const f32x4*)&myA[c*130 + t*32 + qq*8 + 4];
                bf16x8 af = cvt8(lo, hi);
                #pragma unroll
                for (int n = 0; n < 4; ++n)
                    acc[n] = mfma16(af, Bc[t*4 + n], acc[n]);
            }
        };
        #pragma unroll
        for (int gp = 0; gp < 8; ++gp) {
            body(2*gp,     Bcur, Bnext);
            body(2*gp + 1, Bnext, Bcur);
        }
        #pragma unroll
        for (int n = 0; n < 4; ++n) {
            float bv = g1b[n*16 + c];
            #pragma unroll
            for (int j = 0; j < 4; ++j) {
                int r = qq*4 + j, col = n*16 + c;
                myb[r*64 + (col ^ (((r>>1)&3)<<3))] = (__bf16)fmaxf(acc[n][j] + bv, 0.0f);
            }
        }
    }

    // ===== Phase 2: gate = sigmoid(h @ g2w^T + g2b), mod
    float mj[4];
    {
        const __bf16* bB = wsb + PK2 + lane*8;
        bf16x8 a0 = *(const bf16x8*)&myb[c*64 + ((qq*8) ^ swc)];
        bf16x8 a1 = *(const bf16x8*)&myb[c*64 + ((32 + qq*8) ^ swc)];
        bf16x8 b00 = *(const bf16x8*)(bB),      b01 = *(const bf16x8*)(bB+512);
        bf16x8 b10 = *(const bf16x8*)(bB+1024), b11 = *(const bf16x8*)(bB+1536);
        f32x4 ag0 = {}, ag1 = {};
        ag0 = mfma16(a0, b00, ag0); ag1 = mfma16(a0, b01, ag1);
        ag0 = mfma16(a1, b10, ag0); ag1 = mfma16(a1, b11, ag1);
        float s[4] = {0,0,0,0};
        #pragma unroll
        for (int n = 0; n < 2; ++n) {
            float bv = g2b[n*16 + c];
            f32x4 ag = n ? ag1 : ag0;
            #pragma unroll
            for (int j = 0; j < 4; ++j) {
                float gv = 1.0f / (1.0f + __expf(-(ag[j] + bv)));
                gateout[(size_t)(r0 + qq*4 + j)*32 + n*16 + c] = gv;
                s[j] += gv;
            }
        }
        #pragma unroll
        for (int j = 0; j < 4; ++j)
            mj[j] = 0.7f + 0.3f * redsum16(s[j]) * (1.0f/32.0f);
    }

    // ===== Phase 3: xg = LN1(relu((x @ bw^T)*mod + bb))   [16x128, K=512]
    // A hi/lo, B hi only. Depth-1 prefetch (r4 structure).
    f32x4 a3[8] = {};
    {
        const float* aRow0 = x + (size_t)(r0 + srl)*512 + scl*4;
        const float* aRow1 = x + (size_t)(r0 + 8 + srl)*512 + scl*4;
        f32x4 rg[8];
        #pragma unroll
        for (int q = 0; q < 4; ++q) {
            rg[q]   = *(const f32x4*)(aRow0 + q*32);
            rg[4+q] = *(const f32x4*)(aRow1 + q*32);
        }
        for (int g = 0; g < 4; ++g) {
            #pragma unroll
            for (int q = 0; q < 4; ++q) {
                *(f32x4*)&myA[srl*132     + q*32 + scl*4] = rg[q];
                *(f32x4*)&myA[(8+srl)*132 + q*32 + scl*4] = rg[4+q];
            }
            if (g + 1 < 4) {
                #pragma unroll
                for (int q = 0; q < 4; ++q) {
                    rg[q]   = *(const f32x4*)(aRow0 + (g+1)*128 + q*32);
                    rg[4+q] = *(const f32x4*)(aRow1 + (g+1)*128 + q*32);
                }
            }
            #pragma unroll
            for (int t = 0; t < 4; ++t) {
                f32x4 lo = *(const f32x4*)&myA[c*132 + t*32 + qq*8];
                f32x4 hi = *(const f32x4*)&myA[c*132 + t*32 + qq*8 + 4];
                bf16x8 ah, al; split8(lo, hi, ah, al);
                int kt = g*4 + t;
                #pragma unroll
                for (int half = 0; half < 2; ++half) {
                    const __bf16* bt = wsb + PK3 + (size_t)(kt*16 + half*8)*512 + lane*8;
                    #pragma unroll
                    for (int n = 0; n < 4; ++n) {
                        bf16x8 bh = *(const bf16x8*)(bt + n*1024);
                        f32x4 a = a3[half*4 + n];
                        a = mfma16(ah, bh, a); a = mfma16(al, bh, a);
                        a3[half*4 + n] = a;
                    }
                }
            }
        }
        float s[4] = {0,0,0,0}, ss[4] = {0,0,0,0};
        #pragma unroll
        for (int n = 0; n < 8; ++n) {
            float bv = bb[n*16 + c];
            #pragma unroll
            for (int j = 0; j < 4; ++j) {
                float v = fmaxf(a3[n][j]*mj[j] + bv, 0.0f);
                a3[n][j] = v; s[j] += v; ss[j] += v*v;
            }
        }
        float mean[4], rstd[4];
        #pragma unroll
        for (int j = 0; j < 4; ++j) {
            float t = redsum16(s[j]), t2 = redsum16(ss[j]);
            float m = t * (1.0f/128.0f);
            mean[j] = m; rstd[j] = rsqrtf(t2*(1.0f/128.0f) - m*m + 1e-5f);
        }
        #pragma unroll
        for (int n = 0; n < 8; ++n) {
            float g = ln1g[n*16 + c], b2 = ln1b[n*16 + c];
            #pragma unroll
            for (int j = 0; j < 4; ++j) {
                int r = qq*4 + j, col = n*16 + c;
                float y = (a3[n][j] - mean[j]) * rstd[j] * g + b2;
                __bf16 hb = (__bf16)y; __bf16 lb = (__bf16)(y - (float)hb);
                my[r*128 + (col ^ (((r>>1)&3)<<3))] = (u32)bfb(hb) | ((u32)bfb(lb) << 16);
            }
        }
    }

    // ===== Phase 4: f = LN2(relu(xg @ n1w^T + n1b))   [16x64, K=128]
    f32x4 a4[4] = {};
    {
        const __bf16* bB = wsb + PK4 + lane*8;
        #pragma unroll
        for (int t = 0; t < 4; ++t) {
            int base = c*128 + ((t*32 + qq*8) ^ swc);
            u32x4 w0 = *(const u32x4*)&my[base], w1 = *(const u32x4*)&my[base + 4];
            bf16x8 ah, al; unpack8(w0, w1, ah, al);
            const __bf16* bt = bB + t*4096;
            #pragma unroll
            for (int n = 0; n < 4; ++n) {
                bf16x8 bh = *(const bf16x8*)(bt + n*1024);
                f32x4 a = a4[n];
                a = mfma16(ah, bh, a); a = mfma16(al, bh, a);
                a4[n] = a;
            }
        }
        float s[4] = {0,0,0,0}, ss[4] = {0,0,0,0};
        #pragma unroll
        for (int n = 0; n < 4; ++n) {
            float bv = n1b[n*16 + c];
            #pragma unroll
            for (int j = 0; j < 4; ++j) {
                float v = fmaxf(a4[n][j] + bv, 0.0f);
                a4[n][j] = v; s[j] += v; ss[j] += v*v;
            }
        }
        float mean[4], rstd[4];
        #pragma unroll
        for (int j = 0; j < 4; ++j) {
            float t = redsum16(s[j]), t2 = redsum16(ss[j]);
            float m = t * (1.0f/64.0f);
            mean[j] = m; rstd[j] = rsqrtf(t2*(1.0f/64.0f) - m*m + 1e-5f);
        }
        #pragma unroll
        for (int n = 0; n < 4; ++n) {
            float g = ln2g[n*16 + c], b2 = ln2b[n*16 + c];
            #pragma unroll
            for (int j = 0; j < 4; ++j) {
                int r = qq*4 + j, col = n*16 + c;
                float y = (a4[n][j] - mean[j]) * rstd[j] * g + b2;
                __bf16 hb = (__bf16)y; __bf16 lb = (__bf16)(y - (float)hb);
                my[r*64 + (col ^ (((r>>1)&3)<<3))] = (u32)bfb(hb) | ((u32)bfb(lb) << 16);
            }
        }
    }

    // ===== Phase 5: features = relu(f @ mw^T + mb)   [16x32, K=64]
    {
        const __bf16* bB = wsb + PK5 + lane*8;
        f32x4 a5[2] = {};
        #pragma unroll
        for (int t = 0; t < 2; ++t) {
            int base = c*64 + ((t*32 + qq*8) ^ swc);
            u32x4 w0 = *(const u32x4*)&my[base], w1 = *(const u32x4*)&my[base + 4];
            bf16x8 ah, al; unpack8(w0, w1, ah, al);
            const __bf16* bt = bB + t*2048;
            #pragma unroll
            for (int n = 0; n < 2; ++n) {
                bf16x8 bh = *(const bf16x8*)(bt + n*1024);
                f32x4 a = a5[n];
                a = mfma16(ah, bh, a); a = mfma16(al, bh, a);
                a5[n] = a;
            }
        }
        #pragma unroll
        for (int n = 0; n < 2; ++n) {
            float bv = mb[n*16 + c];
            #pragma unroll
            for (int j = 0; j < 4; ++j) {
                int r = qq*4 + j, col = n*16 + c;
                float v = fmaxf(a5[n][j] + bv, 0.0f);
                __bf16 hb = (__bf16)v; __bf16 lb = (__bf16)(v - (float)hb);
                my[r*32 + (col ^ (((r>>1)&3)<<3))] = (u32)bfb(hb) | ((u32)bfb(lb) << 16);
            }
        }
    }

    // ===== Phase 6: dueling heads -> q   [K=32]
    {
        int base = c*32 + ((qq*8) ^ swc);
        u32x4 w0 = *(const u32x4*)&my[base], w1 = *(const u32x4*)&my[base + 4];
        bf16x8 ah, al; unpack8(w0, w1, ah, al);
        const __bf16* bv_ = wsb + PK6V + lane*8;
        const __bf16* ba_ = wsb + PK6A + lane*8;
        bf16x8 vh  = *(const bf16x8*)(bv_);
        bf16x8 ahw = *(const bf16x8*)(ba_);
        f32x4 av = {}, aa = {};
        av = mfma16(ah, vh, av);  av = mfma16(al, vh, av);
        aa = mfma16(ah, ahw, aa); aa = mfma16(al, ahw, aa);
        float v1bc = v1b[c], a1bc = a1b[c], w2 = v2w[c];
        float vb2 = v2b[0];
        float aw0 = a2w[c], aw1 = a2w[16+c], aw2 = a2w[32+c], aw3 = a2w[48+c];
        float ab0 = a2b[0], ab1 = a2b[1], ab2 = a2b[2], ab3 = a2b[3];
        #pragma unroll
        for (int j = 0; j < 4; ++j) {
            float hv = fmaxf(av[j] + v1bc, 0.0f);
            float ha = fmaxf(aa[j] + a1bc, 0.0f);
            float val = redsum16(hv * w2) + vb2;
            float d0 = redsum16(ha * aw0) + ab0;
            float d1 = redsum16(ha * aw1) + ab1;
            float d2 = redsum16(ha * aw2) + ab2;
            float d3 = redsum16(ha * aw3) + ab3;
            float ma = 0.25f * (d0 + d1 + d2 + d3);
            if (c == 0) {
                f32x4 qv = {val + d0 - ma, val + d1 - ma, val + d2 - ma, val + d3 - ma};
                *(f32x4*)(qout + (size_t)(r0 + qq*4 + j)*4) = qv;
            }
        }
    }
}

extern "C" void kernel_launch(void* const* d_in, const int* in_sizes, int n_in,
                              void* d_out, int out_size, void* d_ws, size_t ws_size,
                              hipStream_t stream) {
    (void)in_sizes; (void)n_in; (void)ws_size; (void)out_size;
    const float* x    = (const float*)d_in[0];
    const float* hist = (const float*)d_in[1];
    const float* g1w  = (const float*)d_in[2];
    const float* g1b  = (const float*)d_in[3];
    const float* g2w  = (const float*)d_in[4];
    const float* g2b  = (const float*)d_in[5];
    const float* bw   = (const float*)d_in[6];
    const float* bb   = (const float*)d_in[7];
    const float* ln1g = (const float*)d_in[8];
    const float* ln1b = (const float*)d_in[9];
    const float* n1w  = (const float*)d_in[10];
    const float* n1b  = (const float*)d_in[11];
    const float* ln2g = (const float*)d_in[12];
    const float* ln2b = (const float*)d_in[13];
    const float* mw   = (const float*)d_in[14];
    const float* mb   = (const float*)d_in[15];
    const float* v1w  = (const float*)d_in[16];
    const float* v1b  = (const float*)d_in[17];
    const float* v2w  = (const float*)d_in[18];
    const float* v2b  = (const float*)d_in[19];
    const float* a1w  = (const float*)d_in[20];
    const float* a1b  = (const float*)d_in[21];
    const float* a2w  = (const float*)d_in[22];
    const float* a2b  = (const float*)d_in[23];
    __bf16* wsb = (__bf16*)d_ws;
    float* qout = (float*)d_out;
    float* gateout = qout + (size_t)65536 * 4;

    pack_weights<<<dim3(820), dim3(256), 0, stream>>>(g1w, g2w, bw, n1w, mw, v1w, a1w, wsb);
    gated_dqn_main<<<dim3(1024), dim3(256), 0, stream>>>(
        x, hist, g1b, g2b, bb, ln1g, ln1b, n1b, ln2g, ln2b, mb,
        v1b, v2w, v2b, a1b, a2w, a2b, wsb, qout, gateout);
}

// Round 10
// 164.735 us; speedup vs baseline: 2.6666x; 1.0866x over previous
//
#include <hip/hip_runtime.h>
#include <hip/hip_bf16.h>

typedef float f32x4 __attribute__((ext_vector_type(4)));
typedef __bf16 bf16x8 __attribute__((ext_vector_type(8)));
typedef unsigned int u32;
typedef u32 u32x4 __attribute__((ext_vector_type(4)));

// ws layout (bf16 element offsets)
#define PK1  0        // g1w plain   [kt<64][n<4]     256 KB
#define PK2  131072   // g2w plain   [t<2][n<2]       4 KB
#define PK3  133120   // bw   hi/lo  [kt<16][n<8][hl] 256 KB (main reads hi only)
#define PK4  264192   // n1w  hi/lo  [t<4][n<4][hl]   32 KB  (hi only)
#define PK5  280576   // mw   hi/lo  [t<2][n<2][hl]   8 KB   (hi only)
#define PK6V 284672   // v1w  hi/lo  [hl]             2 KB   (hi only)
#define PK6A 285696   // a1w  hi/lo  [hl]             2 KB   (hi only)

__device__ __forceinline__ f32x4 mfma16(bf16x8 a, bf16x8 b, f32x4 c) {
    return __builtin_amdgcn_mfma_f32_16x16x32_bf16(a, b, c, 0, 0, 0);
}
__device__ __forceinline__ float redsum16(float v) {
    v += __shfl_xor(v, 1); v += __shfl_xor(v, 2);
    v += __shfl_xor(v, 4); v += __shfl_xor(v, 8);
    return v;
}
__device__ __forceinline__ unsigned short bfb(__bf16 b) {
    return __builtin_bit_cast(unsigned short, b);
}
// nontemporal f32x4 load: A-streams are read-once; nt keeps them out of L2
// so the packed-weight working set stays resident (anti-thrash).
__device__ __forceinline__ f32x4 ldnt(const float* p) {
    return __builtin_nontemporal_load((const f32x4*)p);
}
__device__ __forceinline__ bf16x8 cvt8(f32x4 a, f32x4 b) {
    bf16x8 r;
    r[0]=(__bf16)a[0]; r[1]=(__bf16)a[1]; r[2]=(__bf16)a[2]; r[3]=(__bf16)a[3];
    r[4]=(__bf16)b[0]; r[5]=(__bf16)b[1]; r[6]=(__bf16)b[2]; r[7]=(__bf16)b[3];
    return r;
}
__device__ __forceinline__ void split8(f32x4 a, f32x4 b, bf16x8& h, bf16x8& l) {
    #pragma unroll
    for (int e=0;e<4;++e){ __bf16 hb=(__bf16)a[e]; h[e]=hb; l[e]=(__bf16)(a[e]-(float)hb); }
    #pragma unroll
    for (int e=0;e<4;++e){ __bf16 hb=(__bf16)b[e]; h[4+e]=hb; l[4+e]=(__bf16)(b[e]-(float)hb); }
}
__device__ __forceinline__ void unpack8(u32x4 w0, u32x4 w1, bf16x8& h, bf16x8& l) {
    u32 h0=(w0[0]&0xFFFFu)|(w0[1]<<16), h1=(w0[2]&0xFFFFu)|(w0[3]<<16);
    u32 h2=(w1[0]&0xFFFFu)|(w1[1]<<16), h3=(w1[2]&0xFFFFu)|(w1[3]<<16);
    u32 l0=(w0[0]>>16)|(w0[1]&0xFFFF0000u), l1=(w0[2]>>16)|(w0[3]&0xFFFF0000u);
    u32 l2=(w1[0]>>16)|(w1[1]&0xFFFF0000u), l3=(w1[2]>>16)|(w1[3]&0xFFFF0000u);
    u32x4 hv={h0,h1,h2,h3}, lv={l0,l1,l2,l3};
    h=__builtin_bit_cast(bf16x8,hv); l=__builtin_bit_cast(bf16x8,lv);
}

// ---------------- weight pre-pack (one-time per launch, ~5 us) --------------
__device__ __forceinline__ void pack_plain(const float* __restrict__ W, __bf16* __restrict__ dst,
                                           int i, int K, int Nn) {
    int e=i&7, lane=(i>>3)&63, p=i>>9;
    int n=p%Nn, t=p/Nn;
    float v = W[(size_t)(n*16+(lane&15))*K + t*32 + (lane>>4)*8 + e];
    dst[i] = (__bf16)v;
}
__device__ __forceinline__ void pack_hilo(const float* __restrict__ W, __bf16* __restrict__ dst,
                                          int i, int K, int Nn) {
    int e=i&7, lane=(i>>3)&63, p=i>>9;
    int n=p%Nn, t=p/Nn;
    float v = W[(size_t)(n*16+(lane&15))*K + t*32 + (lane>>4)*8 + e];
    __bf16 h = (__bf16)v;
    dst[p*1024 + (i&511)]       = h;
    dst[p*1024 + 512 + (i&511)] = (__bf16)(v - (float)h);
}
__global__ void pack_weights(const float* g1w, const float* g2w, const float* bw,
                             const float* n1w, const float* mw, const float* v1w,
                             const float* a1w, __bf16* wsb) {
    int gi = blockIdx.x*256 + threadIdx.x;
    if      (gi < 131072) pack_plain(g1w, wsb+PK1, gi,          2048, 4);
    else if (gi < 133120) pack_plain(g2w, wsb+PK2, gi-131072,   64,   2);
    else if (gi < 198656) pack_hilo (bw,  wsb+PK3, gi-133120,   512,  8);
    else if (gi < 206848) pack_hilo (n1w, wsb+PK4, gi-198656,   128,  4);
    else if (gi < 208896) pack_hilo (mw,  wsb+PK5, gi-206848,   64,   2);
    else if (gi < 209408) pack_hilo (v1w, wsb+PK6V, gi-208896,  32,   1);
    else if (gi < 209920) pack_hilo (a1w, wsb+PK6A, gi-209408,  32,   1);
}

// ---------------- fused main kernel: barrier-free, 16 rows per wave ---------
// r4 structure (best: 172.9 us) with NONTEMPORAL A loads + NT output stores.
// Pure traffic experiment: A-stream no longer allocates in L2, so packed
// weights stay L2-resident and B-reads stop generating extra HBM fetch.
__global__ __launch_bounds__(256, 4)
void gated_dqn_main(const float* __restrict__ x,   const float* __restrict__ hist,
                    const float* __restrict__ g1b, const float* __restrict__ g2b,
                    const float* __restrict__ bb,  const float* __restrict__ ln1g,
                    const float* __restrict__ ln1b,const float* __restrict__ n1b,
                    const float* __restrict__ ln2g,const float* __restrict__ ln2b,
                    const float* __restrict__ mb,  const float* __restrict__ v1b,
                    const float* __restrict__ v2w, const float* __restrict__ v2b,
                    const float* __restrict__ a1b, const float* __restrict__ a2w,
                    const float* __restrict__ a2b, const __bf16* __restrict__ wsb,
                    float* __restrict__ qout, float* __restrict__ gateout)
{
    __shared__ __align__(16) float scr[4][2112];   // 8.25 KB per wave (aliased views)
    const int tid = threadIdx.x, lane = tid & 63, wv = tid >> 6;
    const int qq = lane >> 4, c = lane & 15;
    const int r0 = (blockIdx.x*4 + wv)*16;
    float*  myA = scr[wv];
    u32*    my  = (u32*)myA;
    __bf16* myb = (__bf16*)myA;
    const int swc = ((c >> 1) & 3) << 3;           // read-side row swizzle (row == c)
    const int srl = lane >> 3, scl = lane & 7;     // coalesced-stage role: row, 16B-chunk

    // ===== Phase 1: h = relu(hist @ g1w^T + g1b)   [16x64, K=2048]
    f32x4 acc[4] = {};
    {
        const float* aRow0 = hist + (size_t)(r0 + srl)*2048 + scl*4;
        const float* aRow1 = hist + (size_t)(r0 + 8 + srl)*2048 + scl*4;
        f32x4 rg[8];
        #pragma unroll
        for (int q = 0; q < 4; ++q) {
            rg[q]   = ldnt(aRow0 + q*32);
            rg[4+q] = ldnt(aRow1 + q*32);
        }
        const __bf16* bB = wsb + PK1 + lane*8;
        bf16x8 cb0 = *(const bf16x8*)(bB),      cb1 = *(const bf16x8*)(bB+512);
        bf16x8 cb2 = *(const bf16x8*)(bB+1024), cb3 = *(const bf16x8*)(bB+1536);
        for (int g = 0; g < 16; ++g) {
            #pragma unroll
            for (int q = 0; q < 4; ++q) {
                *(f32x4*)&myA[srl*132     + q*32 + scl*4] = rg[q];
                *(f32x4*)&myA[(8+srl)*132 + q*32 + scl*4] = rg[4+q];
            }
            if (g + 1 < 16) {
                #pragma unroll
                for (int q = 0; q < 4; ++q) {
                    rg[q]   = ldnt(aRow0 + (g+1)*128 + q*32);
                    rg[4+q] = ldnt(aRow1 + (g+1)*128 + q*32);
                }
            }
            #pragma unroll
            for (int t = 0; t < 4; ++t) {
                int ktn = g*4 + t + 1; if (ktn > 63) ktn = 63;
                const __bf16* btn = bB + (size_t)ktn*2048;
                bf16x8 nb0 = *(const bf16x8*)(btn),      nb1 = *(const bf16x8*)(btn+512);
                bf16x8 nb2 = *(const bf16x8*)(btn+1024), nb3 = *(const bf16x8*)(btn+1536);
                f32x4 lo = *(const f32x4*)&myA[c*132 + t*32 + qq*8];
                f32x4 hi = *(const f32x4*)&myA[c*132 + t*32 + qq*8 + 4];
                bf16x8 af = cvt8(lo, hi);
                acc[0] = mfma16(af, cb0, acc[0]); acc[1] = mfma16(af, cb1, acc[1]);
                acc[2] = mfma16(af, cb2, acc[2]); acc[3] = mfma16(af, cb3, acc[3]);
                cb0 = nb0; cb1 = nb1; cb2 = nb2; cb3 = nb3;
            }
        }
        #pragma unroll
        for (int n = 0; n < 4; ++n) {
            float bv = g1b[n*16 + c];
            #pragma unroll
            for (int j = 0; j < 4; ++j) {
                int r = qq*4 + j, col = n*16 + c;
                myb[r*64 + (col ^ (((r>>1)&3)<<3))] = (__bf16)fmaxf(acc[n][j] + bv, 0.0f);
            }
        }
    }

    // ===== Phase 2: gate = sigmoid(h @ g2w^T + g2b), mod
    float mj[4];
    {
        const __bf16* bB = wsb + PK2 + lane*8;
        bf16x8 a0 = *(const bf16x8*)&myb[c*64 + ((qq*8) ^ swc)];
        bf16x8 a1 = *(const bf16x8*)&myb[c*64 + ((32 + qq*8) ^ swc)];
        bf16x8 b00 = *(const bf16x8*)(bB),      b01 = *(const bf16x8*)(bB+512);
        bf16x8 b10 = *(const bf16x8*)(bB+1024), b11 = *(const bf16x8*)(bB+1536);
        f32x4 ag0 = {}, ag1 = {};
        ag0 = mfma16(a0, b00, ag0); ag1 = mfma16(a0, b01, ag1);
        ag0 = mfma16(a1, b10, ag0); ag1 = mfma16(a1, b11, ag1);
        float s[4] = {0,0,0,0};
        #pragma unroll
        for (int n = 0; n < 2; ++n) {
            float bv = g2b[n*16 + c];
            f32x4 ag = n ? ag1 : ag0;
            #pragma unroll
            for (int j = 0; j < 4; ++j) {
                float gv = 1.0f / (1.0f + __expf(-(ag[j] + bv)));
                __builtin_nontemporal_store(gv,
                    gateout + (size_t)(r0 + qq*4 + j)*32 + n*16 + c);
                s[j] += gv;
            }
        }
        #pragma unroll
        for (int j = 0; j < 4; ++j)
            mj[j] = 0.7f + 0.3f * redsum16(s[j]) * (1.0f/32.0f);
    }

    // ===== Phase 3: xg = LN1(relu((x @ bw^T)*mod + bb))   [16x128, K=512]
    // A hi/lo, B hi only.
    f32x4 a3[8] = {};
    {
        const float* aRow0 = x + (size_t)(r0 + srl)*512 + scl*4;
        const float* aRow1 = x + (size_t)(r0 + 8 + srl)*512 + scl*4;
        f32x4 rg[8];
        #pragma unroll
        for (int q = 0; q < 4; ++q) {
            rg[q]   = ldnt(aRow0 + q*32);
            rg[4+q] = ldnt(aRow1 + q*32);
        }
        for (int g = 0; g < 4; ++g) {
            #pragma unroll
            for (int q = 0; q < 4; ++q) {
                *(f32x4*)&myA[srl*132     + q*32 + scl*4] = rg[q];
                *(f32x4*)&myA[(8+srl)*132 + q*32 + scl*4] = rg[4+q];
            }
            if (g + 1 < 4) {
                #pragma unroll
                for (int q = 0; q < 4; ++q) {
                    rg[q]   = ldnt(aRow0 + (g+1)*128 + q*32);
                    rg[4+q] = ldnt(aRow1 + (g+1)*128 + q*32);
                }
            }
            #pragma unroll
            for (int t = 0; t < 4; ++t) {
                f32x4 lo = *(const f32x4*)&myA[c*132 + t*32 + qq*8];
                f32x4 hi = *(const f32x4*)&myA[c*132 + t*32 + qq*8 + 4];
                bf16x8 ah, al; split8(lo, hi, ah, al);
                int kt = g*4 + t;
                #pragma unroll
                for (int half = 0; half < 2; ++half) {
                    const __bf16* bt = wsb + PK3 + (size_t)(kt*16 + half*8)*512 + lane*8;
                    #pragma unroll
                    for (int n = 0; n < 4; ++n) {
                        bf16x8 bh = *(const bf16x8*)(bt + n*1024);
                        f32x4 a = a3[half*4 + n];
                        a = mfma16(ah, bh, a); a = mfma16(al, bh, a);
                        a3[half*4 + n] = a;
                    }
                }
            }
        }
        float s[4] = {0,0,0,0}, ss[4] = {0,0,0,0};
        #pragma unroll
        for (int n = 0; n < 8; ++n) {
            float bv = bb[n*16 + c];
            #pragma unroll
            for (int j = 0; j < 4; ++j) {
                float v = fmaxf(a3[n][j]*mj[j] + bv, 0.0f);
                a3[n][j] = v; s[j] += v; ss[j] += v*v;
            }
        }
        float mean[4], rstd[4];
        #pragma unroll
        for (int j = 0; j < 4; ++j) {
            float t = redsum16(s[j]), t2 = redsum16(ss[j]);
            float m = t * (1.0f/128.0f);
            mean[j] = m; rstd[j] = rsqrtf(t2*(1.0f/128.0f) - m*m + 1e-5f);
        }
        #pragma unroll
        for (int n = 0; n < 8; ++n) {
            float g = ln1g[n*16 + c], b2 = ln1b[n*16 + c];
            #pragma unroll
            for (int j = 0; j < 4; ++j) {
                int r = qq*4 + j, col = n*16 + c;
                float y = (a3[n][j] - mean[j]) * rstd[j] * g + b2;
                __bf16 hb = (__bf16)y; __bf16 lb = (__bf16)(y - (float)hb);
                my[r*128 + (col ^ (((r>>1)&3)<<3))] = (u32)bfb(hb) | ((u32)bfb(lb) << 16);
            }
        }
    }

    // ===== Phase 4: f = LN2(relu(xg @ n1w^T + n1b))   [16x64, K=128]
    f32x4 a4[4] = {};
    {
        const __bf16* bB = wsb + PK4 + lane*8;
        #pragma unroll
        for (int t = 0; t < 4; ++t) {
            int base = c*128 + ((t*32 + qq*8) ^ swc);
            u32x4 w0 = *(const u32x4*)&my[base], w1 = *(const u32x4*)&my[base + 4];
            bf16x8 ah, al; unpack8(w0, w1, ah, al);
            const __bf16* bt = bB + t*4096;
            #pragma unroll
            for (int n = 0; n < 4; ++n) {
                bf16x8 bh = *(const bf16x8*)(bt + n*1024);
                f32x4 a = a4[n];
                a = mfma16(ah, bh, a); a = mfma16(al, bh, a);
                a4[n] = a;
            }
        }
        float s[4] = {0,0,0,0}, ss[4] = {0,0,0,0};
        #pragma unroll
        for (int n = 0; n < 4; ++n) {
            float bv = n1b[n*16 + c];
            #pragma unroll
            for (int j = 0; j < 4; ++j) {
                float v = fmaxf(a4[n][j] + bv, 0.0f);
                a4[n][j] = v; s[j] += v; ss[j] += v*v;
            }
        }
        float mean[4], rstd[4];
        #pragma unroll
        for (int j = 0; j < 4; ++j) {
            float t = redsum16(s[j]), t2 = redsum16(ss[j]);
            float m = t * (1.0f/64.0f);
            mean[j] = m; rstd[j] = rsqrtf(t2*(1.0f/64.0f) - m*m + 1e-5f);
        }
        #pragma unroll
        for (int n = 0; n < 4; ++n) {
            float g = ln2g[n*16 + c], b2 = ln2b[n*16 + c];
            #pragma unroll
            for (int j = 0; j < 4; ++j) {
                int r = qq*4 + j, col = n*16 + c;
                float y = (a4[n][j] - mean[j]) * rstd[j] * g + b2;
                __bf16 hb = (__bf16)y; __bf16 lb = (__bf16)(y - (float)hb);
                my[r*64 + (col ^ (((r>>1)&3)<<3))] = (u32)bfb(hb) | ((u32)bfb(lb) << 16);
            }
        }
    }

    // ===== Phase 5: features = relu(f @ mw^T + mb)   [16x32, K=64]
    {
        const __bf16* bB = wsb + PK5 + lane*8;
        f32x4 a5[2] = {};
        #pragma unroll
        for (int t = 0; t < 2; ++t) {
            int base = c*64 + ((t*32 + qq*8) ^ swc);
            u32x4 w0 = *(const u32x4*)&my[base], w1 = *(const u32x4*)&my[base + 4];
            bf16x8 ah, al; unpack8(w0, w1, ah, al);
            const __bf16* bt = bB + t*2048;
            #pragma unroll
            for (int n = 0; n < 2; ++n) {
                bf16x8 bh = *(const bf16x8*)(bt + n*1024);
                f32x4 a = a5[n];
                a = mfma16(ah, bh, a); a = mfma16(al, bh, a);
                a5[n] = a;
            }
        }
        #pragma unroll
        for (int n = 0; n < 2; ++n) {
            float bv = mb[n*16 + c];
            #pragma unroll
            for (int j = 0; j < 4; ++j) {
                int r = qq*4 + j, col = n*16 + c;
                float v = fmaxf(a5[n][j] + bv, 0.0f);
                __bf16 hb = (__bf16)v; __bf16 lb = (__bf16)(v - (float)hb);
                my[r*32 + (col ^ (((r>>1)&3)<<3))] = (u32)bfb(hb) | ((u32)bfb(lb) << 16);
            }
        }
    }

    // ===== Phase 6: dueling heads -> q   [K=32]
    {
        int base = c*32 + ((qq*8) ^ swc);
        u32x4 w0 = *(const u32x4*)&my[base], w1 = *(const u32x4*)&my[base + 4];
        bf16x8 ah, al; unpack8(w0, w1, ah, al);
        const __bf16* bv_ = wsb + PK6V + lane*8;
        const __bf16* ba_ = wsb + PK6A + lane*8;
        bf16x8 vh  = *(const bf16x8*)(bv_);
        bf16x8 ahw = *(const bf16x8*)(ba_);
        f32x4 av = {}, aa = {};
        av = mfma16(ah, vh, av);  av = mfma16(al, vh, av);
        aa = mfma16(ah, ahw, aa); aa = mfma16(al, ahw, aa);
        float v1bc = v1b[c], a1bc = a1b[c], w2 = v2w[c];
        float vb2 = v2b[0];
        float aw0 = a2w[c], aw1 = a2w[16+c], aw2 = a2w[32+c], aw3 = a2w[48+c];
        float ab0 = a2b[0], ab1 = a2b[1], ab2 = a2b[2], ab3 = a2b[3];
        #pragma unroll
        for (int j = 0; j < 4; ++j) {
            float hv = fmaxf(av[j] + v1bc, 0.0f);
            float ha = fmaxf(aa[j] + a1bc, 0.0f);
            float val = redsum16(hv * w2) + vb2;
            float d0 = redsum16(ha * aw0) + ab0;
            float d1 = redsum16(ha * aw1) + ab1;
            float d2 = redsum16(ha * aw2) + ab2;
            float d3 = redsum16(ha * aw3) + ab3;
            float ma = 0.25f * (d0 + d1 + d2 + d3);
            if (c == 0) {
                f32x4 qv = {val + d0 - ma, val + d1 - ma, val + d2 - ma, val + d3 - ma};
                __builtin_nontemporal_store(qv,
                    (f32x4*)(qout + (size_t)(r0 + qq*4 + j)*4));
            }
        }
    }
}

extern "C" void kernel_launch(void* const* d_in, const int* in_sizes, int n_in,
                              void* d_out, int out_size, void* d_ws, size_t ws_size,
                              hipStream_t stream) {
    (void)in_sizes; (void)n_in; (void)ws_size; (void)out_size;
    const float* x    = (const float*)d_in[0];
    const float* hist = (const float*)d_in[1];
    const float* g1w  = (const float*)d_in[2];
    const float* g1b  = (const float*)d_in[3];
    const float* g2w  = (const float*)d_in[4];
    const float* g2b  = (const float*)d_in[5];
    const float* bw   = (const float*)d_in[6];
    const float* bb   = (const float*)d_in[7];
    const float* ln1g = (const float*)d_in[8];
    const float* ln1b = (const float*)d_in[9];
    const float* n1w  = (const float*)d_in[10];
    const float* n1b  = (const float*)d_in[11];
    const float* ln2g = (const float*)d_in[12];
    const float* ln2b = (const float*)d_in[13];
    const float* mw   = (const float*)d_in[14];
    const float* mb   = (const float*)d_in[15];
    const float* v1w  = (const float*)d_in[16];
    const float* v1b  = (const float*)d_in[17];
    const float* v2w  = (const float*)d_in[18];
    const float* v2b  = (const float*)d_in[19];
    const float* a1w  = (const float*)d_in[20];
    const float* a1b  = (const float*)d_in[21];
    const float* a2w  = (const float*)d_in[22];
    const float* a2b  = (const float*)d_in[23];
    __bf16* wsb = (__bf16*)d_ws;
    float* qout = (float*)d_out;
    float* gateout = qout + (size_t)65536 * 4;

    pack_weights<<<dim3(820), dim3(256), 0, stream>>>(g1w, g2w, bw, n1w, mw, v1w, a1w, wsb);
    gated_dqn_main<<<dim3(1024), dim3(256), 0, stream>>>(
        x, hist, g1b, g2b, bb, ln1g, ln1b, n1b, ln2g, ln2b, mb,
        v1b, v2w, v2b, a1b, a2w, a2b, wsb, qout, gateout);
}

// Round 11
// 161.232 us; speedup vs baseline: 2.7246x; 1.0217x over previous
//
#include <hip/hip_runtime.h>
#include <hip/hip_bf16.h>

typedef float f32x4 __attribute__((ext_vector_type(4)));
typedef __bf16 bf16x8 __attribute__((ext_vector_type(8)));
typedef unsigned int u32;
typedef u32 u32x4 __attribute__((ext_vector_type(4)));

// ws layout (bf16 element offsets)
#define PK1  0        // g1w plain   [kt<64][n<4]     256 KB
#define PK2  131072   // g2w plain   [t<2][n<2]       4 KB
#define PK3  133120   // bw   hi/lo  [kt<16][n<8][hl] 256 KB (main reads hi only)
#define PK4  264192   // n1w  hi/lo  [t<4][n<4][hl]   32 KB  (hi only)
#define PK5  280576   // mw   hi/lo  [t<2][n<2][hl]   8 KB   (hi only)
#define PK6V 284672   // v1w  hi/lo  [hl]             2 KB   (hi only)
#define PK6A 285696   // a1w  hi/lo  [hl]             2 KB   (hi only)

__device__ __forceinline__ f32x4 mfma16(bf16x8 a, bf16x8 b, f32x4 c) {
    return __builtin_amdgcn_mfma_f32_16x16x32_bf16(a, b, c, 0, 0, 0);
}
__device__ __forceinline__ float redsum16(float v) {
    v += __shfl_xor(v, 1); v += __shfl_xor(v, 2);
    v += __shfl_xor(v, 4); v += __shfl_xor(v, 8);
    return v;
}
__device__ __forceinline__ unsigned short bfb(__bf16 b) {
    return __builtin_bit_cast(unsigned short, b);
}
// nontemporal f32x4 load: A-streams are read-once; nt keeps them out of L2
__device__ __forceinline__ f32x4 ldnt(const float* p) {
    return __builtin_nontemporal_load((const f32x4*)p);
}
__device__ __forceinline__ bf16x8 cvt8(f32x4 a, f32x4 b) {
    bf16x8 r;
    r[0]=(__bf16)a[0]; r[1]=(__bf16)a[1]; r[2]=(__bf16)a[2]; r[3]=(__bf16)a[3];
    r[4]=(__bf16)b[0]; r[5]=(__bf16)b[1]; r[6]=(__bf16)b[2]; r[7]=(__bf16)b[3];
    return r;
}
__device__ __forceinline__ void split8(f32x4 a, f32x4 b, bf16x8& h, bf16x8& l) {
    #pragma unroll
    for (int e=0;e<4;++e){ __bf16 hb=(__bf16)a[e]; h[e]=hb; l[e]=(__bf16)(a[e]-(float)hb); }
    #pragma unroll
    for (int e=0;e<4;++e){ __bf16 hb=(__bf16)b[e]; h[4+e]=hb; l[4+e]=(__bf16)(b[e]-(float)hb); }
}
__device__ __forceinline__ void unpack8(u32x4 w0, u32x4 w1, bf16x8& h, bf16x8& l) {
    u32 h0=(w0[0]&0xFFFFu)|(w0[1]<<16), h1=(w0[2]&0xFFFFu)|(w0[3]<<16);
    u32 h2=(w1[0]&0xFFFFu)|(w1[1]<<16), h3=(w1[2]&0xFFFFu)|(w1[3]<<16);
    u32 l0=(w0[0]>>16)|(w0[1]&0xFFFF0000u), l1=(w0[2]>>16)|(w0[3]&0xFFFF0000u);
    u32 l2=(w1[0]>>16)|(w1[1]&0xFFFF0000u), l3=(w1[2]>>16)|(w1[3]&0xFFFF0000u);
    u32x4 hv={h0,h1,h2,h3}, lv={l0,l1,l2,l3};
    h=__builtin_bit_cast(bf16x8,hv); l=__builtin_bit_cast(bf16x8,lv);
}

// ---------------- weight pre-pack (one-time per launch, ~5 us) --------------
__device__ __forceinline__ void pack_plain(const float* __restrict__ W, __bf16* __restrict__ dst,
                                           int i, int K, int Nn) {
    int e=i&7, lane=(i>>3)&63, p=i>>9;
    int n=p%Nn, t=p/Nn;
    float v = W[(size_t)(n*16+(lane&15))*K + t*32 + (lane>>4)*8 + e];
    dst[i] = (__bf16)v;
}
__device__ __forceinline__ void pack_hilo(const float* __restrict__ W, __bf16* __restrict__ dst,
                                          int i, int K, int Nn) {
    int e=i&7, lane=(i>>3)&63, p=i>>9;
    int n=p%Nn, t=p/Nn;
    float v = W[(size_t)(n*16+(lane&15))*K + t*32 + (lane>>4)*8 + e];
    __bf16 h = (__bf16)v;
    dst[p*1024 + (i&511)]       = h;
    dst[p*1024 + 512 + (i&511)] = (__bf16)(v - (float)h);
}
__global__ void pack_weights(const float* g1w, const float* g2w, const float* bw,
                             const float* n1w, const float* mw, const float* v1w,
                             const float* a1w, __bf16* wsb) {
    int gi = blockIdx.x*256 + threadIdx.x;
    if      (gi < 131072) pack_plain(g1w, wsb+PK1, gi,          2048, 4);
    else if (gi < 133120) pack_plain(g2w, wsb+PK2, gi-131072,   64,   2);
    else if (gi < 198656) pack_hilo (bw,  wsb+PK3, gi-133120,   512,  8);
    else if (gi < 206848) pack_hilo (n1w, wsb+PK4, gi-198656,   128,  4);
    else if (gi < 208896) pack_hilo (mw,  wsb+PK5, gi-206848,   64,   2);
    else if (gi < 209408) pack_hilo (v1w, wsb+PK6V, gi-208896,  32,   1);
    else if (gi < 209920) pack_hilo (a1w, wsb+PK6A, gi-209408,  32,   1);
}

// ---------------- fused main kernel: barrier-free, 16 rows per wave ---------
// Phase 1: depth-2 A prefetch (rgA/rgB) + register-B ping-pong (Bc/Bn) with
// issue order {stage A(g), B(g+1), A(g+2), MFMA w/ B(g)} -- every vmcnt wait
// targets loads >=1-2 group-periods old, so the in-order FIFO never drains
// the young A stream. A loads nontemporal (r10 win preserved).
__global__ __launch_bounds__(256, 2)
void gated_dqn_main(const float* __restrict__ x,   const float* __restrict__ hist,
                    const float* __restrict__ g1b, const float* __restrict__ g2b,
                    const float* __restrict__ bb,  const float* __restrict__ ln1g,
                    const float* __restrict__ ln1b,const float* __restrict__ n1b,
                    const float* __restrict__ ln2g,const float* __restrict__ ln2b,
                    const float* __restrict__ mb,  const float* __restrict__ v1b,
                    const float* __restrict__ v2w, const float* __restrict__ v2b,
                    const float* __restrict__ a1b, const float* __restrict__ a2w,
                    const float* __restrict__ a2b, const __bf16* __restrict__ wsb,
                    float* __restrict__ qout, float* __restrict__ gateout)
{
    __shared__ __align__(16) float scr[4][2112];   // 8.25 KB per wave (aliased views)
    const int tid = threadIdx.x, lane = tid & 63, wv = tid >> 6;
    const int qq = lane >> 4, c = lane & 15;
    const int r0 = (blockIdx.x*4 + wv)*16;
    float*  myA = scr[wv];
    u32*    my  = (u32*)myA;
    __bf16* myb = (__bf16*)myA;
    const int swc = ((c >> 1) & 3) << 3;           // read-side row swizzle (row == c)
    const int srl = lane >> 3, scl = lane & 7;     // coalesced-stage role: row, 16B-chunk

    // ===== Phase 1: h = relu(hist @ g1w^T + g1b)   [16x64, K=2048]
    f32x4 acc[4] = {};
    {
        const float* aRow0 = hist + (size_t)(r0 + srl)*2048 + scl*4;
        const float* aRow1 = hist + (size_t)(r0 + 8 + srl)*2048 + scl*4;
        const __bf16* bB = wsb + PK1 + lane*8;
        f32x4 rgA[8], rgB[8];
        bf16x8 Bc[16], Bn[16];
        // prologue FIFO order: B(0), A(0), A(1)
        #pragma unroll
        for (int i = 0; i < 16; ++i) Bc[i] = *(const bf16x8*)(bB + (size_t)i*512);
        #pragma unroll
        for (int q = 0; q < 4; ++q) {
            rgA[q]   = ldnt(aRow0 + q*32);
            rgA[4+q] = ldnt(aRow1 + q*32);
        }
        #pragma unroll
        for (int q = 0; q < 4; ++q) {
            rgB[q]   = ldnt(aRow0 + 128 + q*32);
            rgB[4+q] = ldnt(aRow1 + 128 + q*32);
        }
        auto body = [&](int g, f32x4* rgS, bf16x8* BcL, bf16x8* BnL) {
            // stage A(g): these regs were loaded TWO bodies ago -> no young drain
            #pragma unroll
            for (int q = 0; q < 4; ++q) {
                *(f32x4*)&myA[srl*132     + q*32 + scl*4] = rgS[q];
                *(f32x4*)&myA[(8+srl)*132 + q*32 + scl*4] = rgS[4+q];
            }
            if (g + 1 < 16) {                       // B(g+1) BEFORE A(g+2)
                #pragma unroll
                for (int i = 0; i < 16; ++i)
                    BnL[i] = *(const bf16x8*)(bB + (size_t)(g+1)*8192 + i*512);
            }
            if (g + 2 < 16) {                       // A(g+2) -> just-staged regs
                #pragma unroll
                for (int q = 0; q < 4; ++q) {
                    rgS[q]   = ldnt(aRow0 + (g+2)*128 + q*32);
                    rgS[4+q] = ldnt(aRow1 + (g+2)*128 + q*32);
                }
            }
            // compute with B(g) in registers: only waits on LDS + old B
            #pragma unroll
            for (int t = 0; t < 4; ++t) {
                f32x4 lo = *(const f32x4*)&myA[c*132 + t*32 + qq*8];
                f32x4 hi = *(const f32x4*)&myA[c*132 + t*32 + qq*8 + 4];
                bf16x8 af = cvt8(lo, hi);
                #pragma unroll
                for (int n = 0; n < 4; ++n)
                    acc[n] = mfma16(af, BcL[t*4 + n], acc[n]);
            }
        };
        #pragma unroll
        for (int gp = 0; gp < 8; ++gp) {
            body(2*gp,     rgA, Bc, Bn);
            body(2*gp + 1, rgB, Bn, Bc);
        }
        #pragma unroll
        for (int n = 0; n < 4; ++n) {
            float bv = g1b[n*16 + c];
            #pragma unroll
            for (int j = 0; j < 4; ++j) {
                int r = qq*4 + j, col = n*16 + c;
                myb[r*64 + (col ^ (((r>>1)&3)<<3))] = (__bf16)fmaxf(acc[n][j] + bv, 0.0f);
            }
        }
    }

    // ===== Phase 2: gate = sigmoid(h @ g2w^T + g2b), mod
    float mj[4];
    {
        const __bf16* bB = wsb + PK2 + lane*8;
        bf16x8 a0 = *(const bf16x8*)&myb[c*64 + ((qq*8) ^ swc)];
        bf16x8 a1 = *(const bf16x8*)&myb[c*64 + ((32 + qq*8) ^ swc)];
        bf16x8 b00 = *(const bf16x8*)(bB),      b01 = *(const bf16x8*)(bB+512);
        bf16x8 b10 = *(const bf16x8*)(bB+1024), b11 = *(const bf16x8*)(bB+1536);
        f32x4 ag0 = {}, ag1 = {};
        ag0 = mfma16(a0, b00, ag0); ag1 = mfma16(a0, b01, ag1);
        ag0 = mfma16(a1, b10, ag0); ag1 = mfma16(a1, b11, ag1);
        float s[4] = {0,0,0,0};
        #pragma unroll
        for (int n = 0; n < 2; ++n) {
            float bv = g2b[n*16 + c];
            f32x4 ag = n ? ag1 : ag0;
            #pragma unroll
            for (int j = 0; j < 4; ++j) {
                float gv = 1.0f / (1.0f + __expf(-(ag[j] + bv)));
                __builtin_nontemporal_store(gv,
                    gateout + (size_t)(r0 + qq*4 + j)*32 + n*16 + c);
                s[j] += gv;
            }
        }
        #pragma unroll
        for (int j = 0; j < 4; ++j)
            mj[j] = 0.7f + 0.3f * redsum16(s[j]) * (1.0f/32.0f);
    }

    // ===== Phase 3: xg = LN1(relu((x @ bw^T)*mod + bb))   [16x128, K=512]
    // A hi/lo, B hi only.
    f32x4 a3[8] = {};
    {
        const float* aRow0 = x + (size_t)(r0 + srl)*512 + scl*4;
        const float* aRow1 = x + (size_t)(r0 + 8 + srl)*512 + scl*4;
        f32x4 rg[8];
        #pragma unroll
        for (int q = 0; q < 4; ++q) {
            rg[q]   = ldnt(aRow0 + q*32);
            rg[4+q] = ldnt(aRow1 + q*32);
        }
        for (int g = 0; g < 4; ++g) {
            #pragma unroll
            for (int q = 0; q < 4; ++q) {
                *(f32x4*)&myA[srl*132     + q*32 + scl*4] = rg[q];
                *(f32x4*)&myA[(8+srl)*132 + q*32 + scl*4] = rg[4+q];
            }
            if (g + 1 < 4) {
                #pragma unroll
                for (int q = 0; q < 4; ++q) {
                    rg[q]   = ldnt(aRow0 + (g+1)*128 + q*32);
                    rg[4+q] = ldnt(aRow1 + (g+1)*128 + q*32);
                }
            }
            #pragma unroll
            for (int t = 0; t < 4; ++t) {
                f32x4 lo = *(const f32x4*)&myA[c*132 + t*32 + qq*8];
                f32x4 hi = *(const f32x4*)&myA[c*132 + t*32 + qq*8 + 4];
                bf16x8 ah, al; split8(lo, hi, ah, al);
                int kt = g*4 + t;
                #pragma unroll
                for (int half = 0; half < 2; ++half) {
                    const __bf16* bt = wsb + PK3 + (size_t)(kt*16 + half*8)*512 + lane*8;
                    #pragma unroll
                    for (int n = 0; n < 4; ++n) {
                        bf16x8 bh = *(const bf16x8*)(bt + n*1024);
                        f32x4 a = a3[half*4 + n];
                        a = mfma16(ah, bh, a); a = mfma16(al, bh, a);
                        a3[half*4 + n] = a;
                    }
                }
            }
        }
        float s[4] = {0,0,0,0}, ss[4] = {0,0,0,0};
        #pragma unroll
        for (int n = 0; n < 8; ++n) {
            float bv = bb[n*16 + c];
            #pragma unroll
            for (int j = 0; j < 4; ++j) {
                float v = fmaxf(a3[n][j]*mj[j] + bv, 0.0f);
                a3[n][j] = v; s[j] += v; ss[j] += v*v;
            }
        }
        float mean[4], rstd[4];
        #pragma unroll
        for (int j = 0; j < 4; ++j) {
            float t = redsum16(s[j]), t2 = redsum16(ss[j]);
            float m = t * (1.0f/128.0f);
            mean[j] = m; rstd[j] = rsqrtf(t2*(1.0f/128.0f) - m*m + 1e-5f);
        }
        #pragma unroll
        for (int n = 0; n < 8; ++n) {
            float g = ln1g[n*16 + c], b2 = ln1b[n*16 + c];
            #pragma unroll
            for (int j = 0; j < 4; ++j) {
                int r = qq*4 + j, col = n*16 + c;
                float y = (a3[n][j] - mean[j]) * rstd[j] * g + b2;
                __bf16 hb = (__bf16)y; __bf16 lb = (__bf16)(y - (float)hb);
                my[r*128 + (col ^ (((r>>1)&3)<<3))] = (u32)bfb(hb) | ((u32)bfb(lb) << 16);
            }
        }
    }

    // ===== Phase 4: f = LN2(relu(xg @ n1w^T + n1b))   [16x64, K=128]
    f32x4 a4[4] = {};
    {
        const __bf16* bB = wsb + PK4 + lane*8;
        #pragma unroll
        for (int t = 0; t < 4; ++t) {
            int base = c*128 + ((t*32 + qq*8) ^ swc);
            u32x4 w0 = *(const u32x4*)&my[base], w1 = *(const u32x4*)&my[base + 4];
            bf16x8 ah, al; unpack8(w0, w1, ah, al);
            const __bf16* bt = bB + t*4096;
            #pragma unroll
            for (int n = 0; n < 4; ++n) {
                bf16x8 bh = *(const bf16x8*)(bt + n*1024);
                f32x4 a = a4[n];
                a = mfma16(ah, bh, a); a = mfma16(al, bh, a);
                a4[n] = a;
            }
        }
        float s[4] = {0,0,0,0}, ss[4] = {0,0,0,0};
        #pragma unroll
        for (int n = 0; n < 4; ++n) {
            float bv = n1b[n*16 + c];
            #pragma unroll
            for (int j = 0; j < 4; ++j) {
                float v = fmaxf(a4[n][j] + bv, 0.0f);
                a4[n][j] = v; s[j] += v; ss[j] += v*v;
            }
        }
        float mean[4], rstd[4];
        #pragma unroll
        for (int j = 0; j < 4; ++j) {
            float t = redsum16(s[j]), t2 = redsum16(ss[j]);
            float m = t * (1.0f/64.0f);
            mean[j] = m; rstd[j] = rsqrtf(t2*(1.0f/64.0f) - m*m + 1e-5f);
        }
        #pragma unroll
        for (int n = 0; n < 4; ++n) {
            float g = ln2g[n*16 + c], b2 = ln2b[n*16 + c];
            #pragma unroll
            for (int j = 0; j < 4; ++j) {
                int r = qq*4 + j, col = n*16 + c;
                float y = (a4[n][j] - mean[j]) * rstd[j] * g + b2;
                __bf16 hb = (__bf16)y; __bf16 lb = (__bf16)(y - (float)hb);
                my[r*64 + (col ^ (((r>>1)&3)<<3))] = (u32)bfb(hb) | ((u32)bfb(lb) << 16);
            }
        }
    }

    // ===== Phase 5: features = relu(f @ mw^T + mb)   [16x32, K=64]
    {
        const __bf16* bB = wsb + PK5 + lane*8;
        f32x4 a5[2] = {};
        #pragma unroll
        for (int t = 0; t < 2; ++t) {
            int base = c*64 + ((t*32 + qq*8) ^ swc);
            u32x4 w0 = *(const u32x4*)&my[base], w1 = *(const u32x4*)&my[base + 4];
            bf16x8 ah, al; unpack8(w0, w1, ah, al);
            const __bf16* bt = bB + t*2048;
            #pragma unroll
            for (int n = 0; n < 2; ++n) {
                bf16x8 bh = *(const bf16x8*)(bt + n*1024);
                f32x4 a = a5[n];
                a = mfma16(ah, bh, a); a = mfma16(al, bh, a);
                a5[n] = a;
            }
        }
        #pragma unroll
        for (int n = 0; n < 2; ++n) {
            float bv = mb[n*16 + c];
            #pragma unroll
            for (int j = 0; j < 4; ++j) {
                int r = qq*4 + j, col = n*16 + c;
                float v = fmaxf(a5[n][j] + bv, 0.0f);
                __bf16 hb = (__bf16)v; __bf16 lb = (__bf16)(v - (float)hb);
                my[r*32 + (col ^ (((r>>1)&3)<<3))] = (u32)bfb(hb) | ((u32)bfb(lb) << 16);
            }
        }
    }

    // ===== Phase 6: dueling heads -> q   [K=32]
    {
        int base = c*32 + ((qq*8) ^ swc);
        u32x4 w0 = *(const u32x4*)&my[base], w1 = *(const u32x4*)&my[base + 4];
        bf16x8 ah, al; unpack8(w0, w1, ah, al);
        const __bf16* bv_ = wsb + PK6V + lane*8;
        const __bf16* ba_ = wsb + PK6A + lane*8;
        bf16x8 vh  = *(const bf16x8*)(bv_);
        bf16x8 ahw = *(const bf16x8*)(ba_);
        f32x4 av = {}, aa = {};
        av = mfma16(ah, vh, av);  av = mfma16(al, vh, av);
        aa = mfma16(ah, ahw, aa); aa = mfma16(al, ahw, aa);
        float v1bc = v1b[c], a1bc = a1b[c], w2 = v2w[c];
        float vb2 = v2b[0];
        float aw0 = a2w[c], aw1 = a2w[16+c], aw2 = a2w[32+c], aw3 = a2w[48+c];
        float ab0 = a2b[0], ab1 = a2b[1], ab2 = a2b[2], ab3 = a2b[3];
        #pragma unroll
        for (int j = 0; j < 4; ++j) {
            float hv = fmaxf(av[j] + v1bc, 0.0f);
            float ha = fmaxf(aa[j] + a1bc, 0.0f);
            float val = redsum16(hv * w2) + vb2;
            float d0 = redsum16(ha * aw0) + ab0;
            float d1 = redsum16(ha * aw1) + ab1;
            float d2 = redsum16(ha * aw2) + ab2;
            float d3 = redsum16(ha * aw3) + ab3;
            float ma = 0.25f * (d0 + d1 + d2 + d3);
            if (c == 0) {
                f32x4 qv = {val + d0 - ma, val + d1 - ma, val + d2 - ma, val + d3 - ma};
                __builtin_nontemporal_store(qv,
                    (f32x4*)(qout + (size_t)(r0 + qq*4 + j)*4));
            }
        }
    }
}

extern "C" void kernel_launch(void* const* d_in, const int* in_sizes, int n_in,
                              void* d_out, int out_size, void* d_ws, size_t ws_size,
                              hipStream_t stream) {
    (void)in_sizes; (void)n_in; (void)ws_size; (void)out_size;
    const float* x    = (const float*)d_in[0];
    const float* hist = (const float*)d_in[1];
    const float* g1w  = (const float*)d_in[2];
    const float* g1b  = (const float*)d_in[3];
    const float* g2w  = (const float*)d_in[4];
    const float* g2b  = (const float*)d_in[5];
    const float* bw   = (const float*)d_in[6];
    const float* bb   = (const float*)d_in[7];
    const float* ln1g = (const float*)d_in[8];
    const float* ln1b = (const float*)d_in[9];
    const float* n1w  = (const float*)d_in[10];
    const float* n1b  = (const float*)d_in[11];
    const float* ln2g = (const float*)d_in[12];
    const float* ln2b = (const float*)d_in[13];
    const float* mw   = (const float*)d_in[14];
    const float* mb   = (const float*)d_in[15];
    const float* v1w  = (const float*)d_in[16];
    const float* v1b  = (const float*)d_in[17];
    const float* v2w  = (const float*)d_in[18];
    const float* v2b  = (const float*)d_in[19];
    const float* a1w  = (const float*)d_in[20];
    const float* a1b  = (const float*)d_in[21];
    const float* a2w  = (const float*)d_in[22];
    const float* a2b  = (const float*)d_in[23];
    __bf16* wsb = (__bf16*)d_ws;
    float* qout = (float*)d_out;
    float* gateout = qout + (size_t)65536 * 4;

    pack_weights<<<dim3(820), dim3(256), 0, stream>>>(g1w, g2w, bw, n1w, mw, v1w, a1w, wsb);
    gated_dqn_main<<<dim3(1024), dim3(256), 0, stream>>>(
        x, hist, g1b, g2b, bb, ln1g, ln1b, n1b, ln2g, ln2b, mb,
        v1b, v2w, v2b, a1b, a2w, a2b, wsb, qout, gateout);
}